// Round 1
// 165.770 us; speedup vs baseline: 1.0037x; 1.0037x over previous
//
#include <hip/hip_runtime.h>

// VectorQuantizer: N=65536 rows, D=256, K=1024 codes, fp32 in/out.
// argmin_k ||x-e_k||^2 == argmax_k (x.e_k - 0.5*||e_k||^2).
// Code-split restructure: each wave owns 64 rows x 512 codes (row-pair p,
// code-half h). Each LDS A-fragment (ds_read_b128) feeds TWO MFMAs
// (row-groups A/B) -> LDS read traffic per CU halved vs 32-row waves;
// main loop becomes MFMA-limited with 2 waves/SIMD intact.
// Per-row top-3 merged across the two code-half waves via small LDS
// exchange; exact fp32 rescue when approx top-2 margin <= 0.25 (identical
// numerics to previous verified kernel: single fp16 term, |err| <~ 0.02,
// 10-bit code-in-mantissa packing quant <= 0.03).

#define K_EMB  1024
#define D_DIM  256
#define N_ROWS 65536

typedef unsigned int u32;
typedef unsigned long long u64;
typedef __attribute__((ext_vector_type(8)))  _Float16 f16x8;
typedef __attribute__((ext_vector_type(4)))  _Float16 f16x4;
typedef __attribute__((ext_vector_type(16))) float    f32x16;

__device__ __forceinline__ u32 f32_sortable(float f) {
    u32 u = __float_as_uint(f);
    return u ^ ((u32)((int)u >> 31) | 0x80000000u);
}
__device__ __forceinline__ float f32_unsort(u32 u) {
    u32 v = (u & 0x80000000u) ? (u ^ 0x80000000u) : ~u;
    return __uint_as_float(v);
}

#define GLDS(gp, lp) __builtin_amdgcn_global_load_lds( \
    (const __attribute__((address_space(1))) void*)(gp), \
    (__attribute__((address_space(3))) void*)(lp), 16, 0, 0)

// ---- prep: emb fp32 -> fp16; cn2[code]={-cnh,-cnl,0..}; exact fp32 cnorm ----
__global__ void vq_prep(const float* __restrict__ emb,
                        _Float16* __restrict__ ehi,
                        _Float16* __restrict__ cn2,
                        float* __restrict__ cnormf) {
    int gid = blockIdx.x * 256 + threadIdx.x;
    int code = gid >> 6, lane = gid & 63;
    float4 v = ((const float4*)(emb + (size_t)code * D_DIM))[lane];
    f16x4 hv = {(_Float16)v.x, (_Float16)v.y, (_Float16)v.z, (_Float16)v.w};
    ((f16x4*)(ehi + (size_t)code * D_DIM))[lane] = hv;
    float s = v.x * v.x + v.y * v.y + v.z * v.z + v.w * v.w;
    #pragma unroll
    for (int off = 32; off > 0; off >>= 1) s += __shfl_down(s, off, 64);
    if (lane == 0) {
        float cn = 0.5f * s;
        cnormf[code] = cn;
        _Float16 ch = (_Float16)cn;
        _Float16 cl = (_Float16)(cn - (float)ch);
        f16x8 e = {};
        e[0] = (_Float16)(-(float)ch);
        e[1] = (_Float16)(-(float)cl);
        ((f16x8*)cn2)[code] = e;
    }
}

// ---- fused main: GEMM + top3 + cross-wave merge + rescue + gather ----
__global__ __launch_bounds__(256, 2) void vq_main(
    const float* __restrict__ x, const float* __restrict__ emb,
    const _Float16* __restrict__ eh, const _Float16* __restrict__ cn2,
    const float* __restrict__ cnormf,
    float* __restrict__ outq, float* __restrict__ outi)
{
    // T[parity][code-half][kc 0..31][code 0..31][8 halfs] : 4 x 16 KB tiles
    __shared__ _Float16 T[2][2][8192];
    __shared__ u32 xchg[2][128][3];   // [code-half][local row][rank]
    __shared__ int winners[128];

    const int t = threadIdx.x, w = t >> 6, lane = t & 63;
    const int m = lane & 31, kh = lane >> 5;
    const int p = w >> 1;                 // row-pair: local rows p*64 .. p*64+63
    const int h = w & 1;                  // code half: codes h*512 .. h*512+511
    const int blkrow = blockIdx.x * 128;
    const int rowA = blkrow + p * 64 + m; // row-group 0 row for this lane
    const int kh4 = kh * 4;

    // B-operand frags: 64 rows (two groups of 32), k = s*16 + kh*8 + [0..8)
    f16x8 bhA[16], bhB[16];
    {
        const float* xr = x + (size_t)rowA * D_DIM + kh * 8;
        #pragma unroll
        for (int s = 0; s < 16; s++) {
            float4 v0 = *(const float4*)(xr + s * 16);
            float4 v1 = *(const float4*)(xr + s * 16 + 4);
            bhA[s] = (f16x8){(_Float16)v0.x, (_Float16)v0.y, (_Float16)v0.z, (_Float16)v0.w,
                             (_Float16)v1.x, (_Float16)v1.y, (_Float16)v1.z, (_Float16)v1.w};
            float4 u0 = *(const float4*)(xr + 32 * D_DIM + s * 16);
            float4 u1 = *(const float4*)(xr + 32 * D_DIM + s * 16 + 4);
            bhB[s] = (f16x8){(_Float16)u0.x, (_Float16)u0.y, (_Float16)u0.z, (_Float16)u0.w,
                             (_Float16)u1.x, (_Float16)u1.y, (_Float16)u1.z, (_Float16)u1.w};
        }
    }
    f16x8 xe = {};
    if (kh == 0) { xe[0] = (_Float16)1.0f; xe[1] = (_Float16)1.0f; }

    u32 A1 = 0, A2 = 0, A3 = 0, B1 = 0, B2 = 0, B3 = 0;

    auto t3 = [](u32& c1, u32& c2, u32& c3, u32 pv) {
        u32 u2 = c1 < pv ? c1 : pv;       // min(c1,pv)
        u32 u3 = c2 < pv ? c2 : pv;       // min(c2,pv)
        c1 = c1 > pv ? c1 : pv;
        c2 = u2 > c2 ? u2 : c2;
        c3 = u3 > c3 ? u3 : c3;
    };

    // stage step c: both halves' 16 KB tiles; regions r = w*4+i cover kc pair
    auto stage = [&](int c) {
        const int buf = c & 1;
        #pragma unroll
        for (int hh = 0; hh < 2; hh++) {
            const _Float16* srcb = eh + (size_t)(hh * 512 + c * 32 + m) * D_DIM + (lane >> 5) * 8;
            _Float16* dstb = &T[buf][hh][0];
            #pragma unroll
            for (int i = 0; i < 4; i++) {
                int r = w * 4 + i;
                GLDS(srcb + r * 16, dstb + r * 512);
            }
        }
    };

    // one 32-code step: 16 ds_read_b128, each feeding 2 MFMAs
    auto compute = [&](int buf, f32x16& a0, f32x16& a1, int c) {
        const f16x8* Af = (const f16x8*)&T[buf][h][0];
        f16x8 e = ((const f16x8*)cn2)[h * 512 + c * 32 + m];
        a0 = (f32x16){}; a1 = (f32x16){};
        #pragma unroll
        for (int s = 0; s < 16; s++) {
            f16x8 fa = Af[(2 * s + kh) * 32 + m];
            a0 = __builtin_amdgcn_mfma_f32_32x32x16_f16(fa, bhA[s], a0, 0, 0, 0);
            a1 = __builtin_amdgcn_mfma_f32_32x32x16_f16(fa, bhB[s], a1, 0, 0, 0);
        }
        a0 = __builtin_amdgcn_mfma_f32_32x32x16_f16(e, xe, a0, 0, 0, 0);
        a1 = __builtin_amdgcn_mfma_f32_32x32x16_f16(e, xe, a1, 0, 0, 0);
    };

    auto top3p = [&](const f32x16& a0, const f32x16& a1, int c) {
        const u32 sbase = (u32)(h * 512 + c * 32) + kh4;
        #pragma unroll
        for (int r = 0; r < 16; r++) {
            u32 code = sbase + (r & 3) + 8 * (r >> 2);
            u32 pa = (f32_sortable(a0[r]) & 0xFFFFFC00u) | code;
            t3(A1, A2, A3, pa);
            u32 pb = (f32_sortable(a1[r]) & 0xFFFFFC00u) | code;
            t3(B1, B2, B3, pb);
        }
    };

    f32x16 aA0, aA1, aB0, aB1;
    stage(0);
    for (int cc = 0; cc < 16; cc += 2) {
        __syncthreads();
        if (cc + 1 < 16) stage(cc + 1);
        compute(0, aA0, aA1, cc);
        if (cc) top3p(aB0, aB1, cc - 1);
        __syncthreads();
        if (cc + 2 < 16) stage(cc + 2);
        compute(1, aB0, aB1, cc + 1);
        top3p(aA0, aA1, cc);
    }
    top3p(aB0, aB1, 15);

    // merge the two kh-halves of each row (partner lane = lane ^ 32)
    {
        u32 q1 = (u32)__shfl_xor((int)A1, 32, 64);
        u32 q2 = (u32)__shfl_xor((int)A2, 32, 64);
        u32 q3 = (u32)__shfl_xor((int)A3, 32, 64);
        t3(A1, A2, A3, q1); t3(A1, A2, A3, q2); t3(A1, A2, A3, q3);
        q1 = (u32)__shfl_xor((int)B1, 32, 64);
        q2 = (u32)__shfl_xor((int)B2, 32, 64);
        q3 = (u32)__shfl_xor((int)B3, 32, 64);
        t3(B1, B2, B3, q1); t3(B1, B2, B3, q2); t3(B1, B2, B3, q3);
    }

    // cross-wave (code-half) exchange of per-row top3
    if (kh == 0) {
        int ra = p * 64 + m;
        xchg[h][ra][0] = A1; xchg[h][ra][1] = A2; xchg[h][ra][2] = A3;
        xchg[h][ra + 32][0] = B1; xchg[h][ra + 32][1] = B2; xchg[h][ra + 32][2] = B3;
    }
    __syncthreads();

    // each wave finishes 32 rows: local rows p*64 + h*32 + [0..32)
    const int rl = p * 64 + h * 32 + m;
    u32 c1 = 0, c2 = 0, c3 = 0;
    t3(c1, c2, c3, xchg[0][rl][0]); t3(c1, c2, c3, xchg[0][rl][1]); t3(c1, c2, c3, xchg[0][rl][2]);
    t3(c1, c2, c3, xchg[1][rl][0]); t3(c1, c2, c3, xchg[1][rl][1]); t3(c1, c2, c3, xchg[1][rl][2]);

    // rescue selection: exact fp32 re-eval when approx margin <= 0.25
    float s1f = f32_unsort(c1), s2f = f32_unsort(c2), s3f = f32_unsort(c3);
    u32 i1 = c1 & 1023u, i2 = c2 & 1023u, i3 = c3 & 1023u;
    bool need = (s1f - s2f) <= 0.25f;
    if (kh == 0 && !need) winners[rl] = (int)i1;
    u64 mask = __ballot(kh == 0 && need);
    while (mask) {
        int r = __ffsll((unsigned long long)mask) - 1;
        mask &= mask - 1;
        int row = blkrow + p * 64 + h * 32 + r;
        u32 d1 = (u32)__shfl((int)i1, r, 64);
        u32 d2 = (u32)__shfl((int)i2, r, 64);
        u32 d3 = (u32)__shfl((int)i3, r, 64);
        float g3 = __shfl(s1f - s3f, r, 64);
        int ncand = (g3 <= 0.25f) ? 3 : 2;
        float4 xv = ((const float4*)(x + (size_t)row * D_DIM))[lane];
        float bs = -3.0e38f; int bi = 0x7fffffff;
        u32 cand[3] = {d1, d2, d3};
        for (int q = 0; q < ncand; q++) {
            int ccd = (int)cand[q];
            float4 ev = ((const float4*)(emb + (size_t)ccd * D_DIM))[lane];
            float d = xv.x * ev.x + xv.y * ev.y + xv.z * ev.z + xv.w * ev.w;
            #pragma unroll
            for (int dd = 1; dd < 64; dd <<= 1) d += __shfl_xor(d, dd, 64);
            float sc = d - cnormf[ccd];
            if (sc > bs || (sc == bs && ccd < bi)) { bs = sc; bi = ccd; }
        }
        if (lane == 0) winners[p * 64 + h * 32 + r] = bi;
    }

    // index write + gather (winners slots are wave-private; no barrier needed)
    if (kh == 0) outi[blkrow + rl] = (float)winners[rl];
    const int gbase = p * 64 + h * 32;
    #pragma unroll 8
    for (int r = 0; r < 32; r++) {
        int idx = winners[gbase + r];
        int row = blkrow + gbase + r;
        float4 qv = ((const float4*)(emb + (size_t)idx * D_DIM))[lane];
        ((float4*)(outq + (size_t)row * D_DIM))[lane] = qv;
    }
}

extern "C" void kernel_launch(void* const* d_in, const int* in_sizes, int n_in,
                              void* d_out, int out_size, void* d_ws, size_t ws_size,
                              hipStream_t stream) {
    const float* x   = (const float*)d_in[0];
    const float* emb = (const float*)d_in[1];
    float* outq = (float*)d_out;
    float* outi = outq + (size_t)N_ROWS * D_DIM;

    _Float16* ehi = (_Float16*)d_ws;                              // 512 KB
    _Float16* cn2 = ehi + (size_t)K_EMB * D_DIM;                  // 16 KB
    float* cnormf = (float*)(cn2 + (size_t)K_EMB * 8);            // 4 KB

    vq_prep<<<K_EMB / 4, 256, 0, stream>>>(emb, ehi, cn2, cnormf);
    vq_main<<<N_ROWS / 128, 256, 0, stream>>>(x, emb, ehi, cn2, cnormf,
                                              outq, outi);
}

// Round 2
// 164.386 us; speedup vs baseline: 1.0122x; 1.0084x over previous
//
#include <hip/hip_runtime.h>

// VectorQuantizer: N=65536 rows, D=256, K=1024 codes, fp32 in/out.
// argmin_k ||x-e_k||^2 == argmax_k (x.e_k - 0.5*||e_k||^2).
// R2: occupancy restructure. 512-thread blocks (8 waves = 4 row-groups x
// 2 code-halves), 32 rows x 512 codes per wave -> ~110 unified regs/wave
// (bh[16]=64 VGPR + one f32x16 acc) => 4 waves/SIMD with launch_bounds
// (512,4); 2 blocks/CU (LDS 69 KB) = 16 waves/CU (was 8). Each staged
// LDS tile is read by 4 waves; 1 barrier per 32-code chunk (16 total).
// Numerics identical to verified kernel: single fp16 term (|err|<~0.02),
// 10-bit code-in-mantissa packing (quant <=0.03), exact fp32 rescue when
// approx top-2 margin <= 0.25.

#define K_EMB  1024
#define D_DIM  256
#define N_ROWS 65536

typedef unsigned int u32;
typedef unsigned long long u64;
typedef __attribute__((ext_vector_type(8)))  _Float16 f16x8;
typedef __attribute__((ext_vector_type(4)))  _Float16 f16x4;
typedef __attribute__((ext_vector_type(16))) float    f32x16;

__device__ __forceinline__ u32 f32_sortable(float f) {
    u32 u = __float_as_uint(f);
    return u ^ ((u32)((int)u >> 31) | 0x80000000u);
}
__device__ __forceinline__ float f32_unsort(u32 u) {
    u32 v = (u & 0x80000000u) ? (u ^ 0x80000000u) : ~u;
    return __uint_as_float(v);
}

#define GLDS(gp, lp) __builtin_amdgcn_global_load_lds( \
    (const __attribute__((address_space(1))) void*)(gp), \
    (__attribute__((address_space(3))) void*)(lp), 16, 0, 0)

// ---- prep: emb fp32 -> fp16; cn2[code]={-cnh,-cnl,0..}; exact fp32 cnorm ----
__global__ void vq_prep(const float* __restrict__ emb,
                        _Float16* __restrict__ ehi,
                        _Float16* __restrict__ cn2,
                        float* __restrict__ cnormf) {
    int gid = blockIdx.x * 256 + threadIdx.x;
    int code = gid >> 6, lane = gid & 63;
    float4 v = ((const float4*)(emb + (size_t)code * D_DIM))[lane];
    f16x4 hv = {(_Float16)v.x, (_Float16)v.y, (_Float16)v.z, (_Float16)v.w};
    ((f16x4*)(ehi + (size_t)code * D_DIM))[lane] = hv;
    float s = v.x * v.x + v.y * v.y + v.z * v.z + v.w * v.w;
    #pragma unroll
    for (int off = 32; off > 0; off >>= 1) s += __shfl_down(s, off, 64);
    if (lane == 0) {
        float cn = 0.5f * s;
        cnormf[code] = cn;
        _Float16 ch = (_Float16)cn;
        _Float16 cl = (_Float16)(cn - (float)ch);
        f16x8 e = {};
        e[0] = (_Float16)(-(float)ch);
        e[1] = (_Float16)(-(float)cl);
        ((f16x8*)cn2)[code] = e;
    }
}

// ---- fused main: GEMM + top3 + cross-wave merge + rescue + gather ----
__global__ __launch_bounds__(512, 4) void vq_main(
    const float* __restrict__ x, const float* __restrict__ emb,
    const _Float16* __restrict__ eh, const _Float16* __restrict__ cn2,
    const float* __restrict__ cnormf,
    float* __restrict__ outq, float* __restrict__ outi)
{
    // T[parity][code-half][s 0..15][kh][code 0..31][8 halfs]: 2 x 32 KB
    __shared__ _Float16 T[2][2][8192];
    __shared__ u32 xchg[2][128][3];   // [code-half][local row][rank]
    __shared__ int winners[128];

    const int t = threadIdx.x, w = t >> 6, lane = t & 63;
    const int m = lane & 31, kh = lane >> 5;
    const int p = w >> 1;                 // row-group 0..3 (32 rows each)
    const int h = w & 1;                  // code half: codes h*512..+512
    const int blkrow = blockIdx.x * 128;
    const int myrow = blkrow + p * 32 + m;
    const int kh4 = kh * 4;

    // stage chunk c (32 codes per half) into T[c&1]; wave w covers half h,
    // dim-regions r = p*4 + [0..4)
    auto stage = [&](int c) {
        _Float16* dstb = &T[c & 1][h][0];
        const _Float16* srcb = eh + (size_t)(h * 512 + c * 32 + m) * D_DIM + kh * 8;
        #pragma unroll
        for (int i = 0; i < 4; i++) {
            int r = p * 4 + i;
            GLDS(srcb + r * 16, dstb + r * 512);
        }
    };

    stage(0);   // issue first tile before (and hidden under) the x prologue

    // B-operand frags: x[myrow] in fp16, k = s*16 + kh*8 + [0..8)
    f16x8 bh[16];
    {
        const float* xr = x + (size_t)myrow * D_DIM + kh * 8;
        #pragma unroll
        for (int s = 0; s < 16; s++) {
            float4 v0 = *(const float4*)(xr + s * 16);
            float4 v1 = *(const float4*)(xr + s * 16 + 4);
            bh[s] = (f16x8){(_Float16)v0.x, (_Float16)v0.y, (_Float16)v0.z, (_Float16)v0.w,
                            (_Float16)v1.x, (_Float16)v1.y, (_Float16)v1.z, (_Float16)v1.w};
        }
    }
    f16x8 xe = {};
    if (kh == 0) { xe[0] = (_Float16)1.0f; xe[1] = (_Float16)1.0f; }

    u32 A1 = 0, A2 = 0, A3 = 0;

    auto t3 = [](u32& c1, u32& c2, u32& c3, u32 pv) {
        u32 u2 = c1 < pv ? c1 : pv;       // min(c1,pv)
        u32 u3 = c2 < pv ? c2 : pv;       // min(c2,pv)
        c1 = c1 > pv ? c1 : pv;
        c2 = u2 > c2 ? u2 : c2;
        c3 = u3 > c3 ? u3 : c3;
    };

    // main loop: 16 chunks, ONE barrier per chunk.
    // barrier at top: publishes tile c AND retires the buffer stage(c+1)
    // overwrites (it was last read in chunk c-1).
    for (int c = 0; c < 16; ++c) {
        __syncthreads();
        if (c + 1 < 16) stage(c + 1);
        const f16x8* Af = (const f16x8*)&T[c & 1][h][0];
        f16x8 e = ((const f16x8*)cn2)[h * 512 + c * 32 + m];
        f32x16 a = {};
        #pragma unroll
        for (int s = 0; s < 16; s++) {
            f16x8 fa = Af[(2 * s + kh) * 32 + m];
            a = __builtin_amdgcn_mfma_f32_32x32x16_f16(fa, bh[s], a, 0, 0, 0);
        }
        a = __builtin_amdgcn_mfma_f32_32x32x16_f16(e, xe, a, 0, 0, 0);
        const u32 sbase = (u32)(h * 512 + c * 32) + kh4;
        #pragma unroll
        for (int r = 0; r < 16; r++) {
            u32 code = sbase + (r & 3) + 8 * (r >> 2);
            u32 pk = (f32_sortable(a[r]) & 0xFFFFFC00u) | code;
            t3(A1, A2, A3, pk);
        }
    }

    // merge the two kh-halves of each row (partner lane = lane ^ 32)
    {
        u32 q1 = (u32)__shfl_xor((int)A1, 32, 64);
        u32 q2 = (u32)__shfl_xor((int)A2, 32, 64);
        u32 q3 = (u32)__shfl_xor((int)A3, 32, 64);
        t3(A1, A2, A3, q1); t3(A1, A2, A3, q2); t3(A1, A2, A3, q3);
    }

    // cross-wave (code-half) exchange of per-row top3
    if (kh == 0) {
        int ra = p * 32 + m;
        xchg[h][ra][0] = A1; xchg[h][ra][1] = A2; xchg[h][ra][2] = A3;
    }
    __syncthreads();

    // epilogue: each wave owns 16 rows (local rows w*16 .. w*16+16)
    const int lr = w * 16 + (lane & 15);
    u32 c1 = 0, c2 = 0, c3 = 0;
    #pragma unroll
    for (int hh = 0; hh < 2; hh++) {
        t3(c1, c2, c3, xchg[hh][lr][0]);
        t3(c1, c2, c3, xchg[hh][lr][1]);
        t3(c1, c2, c3, xchg[hh][lr][2]);
    }

    // rescue selection: exact fp32 re-eval when approx margin <= 0.25
    float s1f = f32_unsort(c1), s2f = f32_unsort(c2), s3f = f32_unsort(c3);
    u32 i1 = c1 & 1023u, i2 = c2 & 1023u, i3 = c3 & 1023u;
    const bool act = lane < 16;
    bool need = (s1f - s2f) <= 0.25f;
    if (act && !need) winners[lr] = (int)i1;
    u64 mask = __ballot(act && need);
    while (mask) {
        int r = __ffsll((unsigned long long)mask) - 1;
        mask &= mask - 1;
        int row = blkrow + w * 16 + r;
        u32 d1 = (u32)__shfl((int)i1, r, 64);
        u32 d2 = (u32)__shfl((int)i2, r, 64);
        u32 d3 = (u32)__shfl((int)i3, r, 64);
        float g3 = __shfl(s1f - s3f, r, 64);
        int ncand = (g3 <= 0.25f) ? 3 : 2;
        float4 xv = ((const float4*)(x + (size_t)row * D_DIM))[lane];
        float bs = -3.0e38f; int bi = 0x7fffffff;
        u32 cand[3] = {d1, d2, d3};
        for (int q = 0; q < ncand; q++) {
            int ccd = (int)cand[q];
            float4 ev = ((const float4*)(emb + (size_t)ccd * D_DIM))[lane];
            float d = xv.x * ev.x + xv.y * ev.y + xv.z * ev.z + xv.w * ev.w;
            #pragma unroll
            for (int dd = 1; dd < 64; dd <<= 1) d += __shfl_xor(d, dd, 64);
            float sc = d - cnormf[ccd];
            if (sc > bs || (sc == bs && ccd < bi)) { bs = sc; bi = ccd; }
        }
        if (lane == 0) winners[w * 16 + r] = bi;
    }

    // index write + gather (winners slots are wave-private; no barrier needed)
    if (act) outi[blkrow + lr] = (float)winners[lr];
    #pragma unroll 8
    for (int r = 0; r < 16; r++) {
        int idx = winners[w * 16 + r];
        int row = blkrow + w * 16 + r;
        float4 qv = ((const float4*)(emb + (size_t)idx * D_DIM))[lane];
        ((float4*)(outq + (size_t)row * D_DIM))[lane] = qv;
    }
}

extern "C" void kernel_launch(void* const* d_in, const int* in_sizes, int n_in,
                              void* d_out, int out_size, void* d_ws, size_t ws_size,
                              hipStream_t stream) {
    const float* x   = (const float*)d_in[0];
    const float* emb = (const float*)d_in[1];
    float* outq = (float*)d_out;
    float* outi = outq + (size_t)N_ROWS * D_DIM;

    _Float16* ehi = (_Float16*)d_ws;                              // 512 KB
    _Float16* cn2 = ehi + (size_t)K_EMB * D_DIM;                  // 16 KB
    float* cnormf = (float*)(cn2 + (size_t)K_EMB * 8);            // 4 KB

    vq_prep<<<K_EMB / 4, 256, 0, stream>>>(emb, ehi, cn2, cnormf);
    vq_main<<<N_ROWS / 128, 512, 0, stream>>>(x, emb, ehi, cn2, cnormf,
                                              outq, outi);
}

// Round 3
// 156.929 us; speedup vs baseline: 1.0603x; 1.0475x over previous
//
#include <hip/hip_runtime.h>

// VectorQuantizer: N=65536 rows, D=256, K=1024 codes, fp32 in/out.
// argmin_k ||x-e_k||^2 == argmax_k (x.e_k - 0.5*||e_k||^2).
// R3: coalesced x prologue. R2's per-lane row-strided float4 loads touched
// 64 cache lines per instruction (~13 us/CU of L1 transactions). Now x is
// loaded thread-contiguous (fully coalesced), converted to fp16 in regs,
// staged into T[1] (32 KB, two 64-row passes) with XOR swizzle
// (byte ^= (row&7)<<4), and fragments come back via ds_read_b128
// (4-way conflict, one-time). Main loop / epilogue unchanged from R2:
// 512-thread blocks, 8 waves = 4 row-groups x 2 code-halves, 1 barrier
// per 32-code chunk, exact fp32 rescue when approx top-2 margin <= 0.25.

#define K_EMB  1024
#define D_DIM  256
#define N_ROWS 65536

typedef unsigned int u32;
typedef unsigned long long u64;
typedef __attribute__((ext_vector_type(8)))  _Float16 f16x8;
typedef __attribute__((ext_vector_type(4)))  _Float16 f16x4;
typedef __attribute__((ext_vector_type(16))) float    f32x16;

__device__ __forceinline__ u32 f32_sortable(float f) {
    u32 u = __float_as_uint(f);
    return u ^ ((u32)((int)u >> 31) | 0x80000000u);
}
__device__ __forceinline__ float f32_unsort(u32 u) {
    u32 v = (u & 0x80000000u) ? (u ^ 0x80000000u) : ~u;
    return __uint_as_float(v);
}

#define GLDS(gp, lp) __builtin_amdgcn_global_load_lds( \
    (const __attribute__((address_space(1))) void*)(gp), \
    (__attribute__((address_space(3))) void*)(lp), 16, 0, 0)

// ---- prep: emb fp32 -> fp16; cn2[code]={-cnh,-cnl,0..}; exact fp32 cnorm ----
__global__ void vq_prep(const float* __restrict__ emb,
                        _Float16* __restrict__ ehi,
                        _Float16* __restrict__ cn2,
                        float* __restrict__ cnormf) {
    int gid = blockIdx.x * 256 + threadIdx.x;
    int code = gid >> 6, lane = gid & 63;
    float4 v = ((const float4*)(emb + (size_t)code * D_DIM))[lane];
    f16x4 hv = {(_Float16)v.x, (_Float16)v.y, (_Float16)v.z, (_Float16)v.w};
    ((f16x4*)(ehi + (size_t)code * D_DIM))[lane] = hv;
    float s = v.x * v.x + v.y * v.y + v.z * v.z + v.w * v.w;
    #pragma unroll
    for (int off = 32; off > 0; off >>= 1) s += __shfl_down(s, off, 64);
    if (lane == 0) {
        float cn = 0.5f * s;
        cnormf[code] = cn;
        _Float16 ch = (_Float16)cn;
        _Float16 cl = (_Float16)(cn - (float)ch);
        f16x8 e = {};
        e[0] = (_Float16)(-(float)ch);
        e[1] = (_Float16)(-(float)cl);
        ((f16x8*)cn2)[code] = e;
    }
}

// ---- fused main: GEMM + top3 + cross-wave merge + rescue + gather ----
__global__ __launch_bounds__(512, 4) void vq_main(
    const float* __restrict__ x, const float* __restrict__ emb,
    const _Float16* __restrict__ eh, const _Float16* __restrict__ cn2,
    const float* __restrict__ cnormf,
    float* __restrict__ outq, float* __restrict__ outi)
{
    // T[parity][code-half][s 0..15][kh][code 0..31][8 halfs]: 2 x 32 KB
    __shared__ _Float16 T[2][2][8192];
    __shared__ u32 xchg[2][128][3];   // [code-half][local row][rank]
    __shared__ int winners[128];

    const int t = threadIdx.x, w = t >> 6, lane = t & 63;
    const int m = lane & 31, kh = lane >> 5;
    const int p = w >> 1;                 // row-group 0..3 (32 rows each)
    const int h = w & 1;                  // code half: codes h*512..+512
    const int blkrow = blockIdx.x * 128;
    const int kh4 = kh * 4;

    // stage chunk c (32 codes per half) into T[c&1]; wave w covers half h,
    // dim-regions r = p*4 + [0..4)
    auto stage = [&](int c) {
        _Float16* dstb = &T[c & 1][h][0];
        const _Float16* srcb = eh + (size_t)(h * 512 + c * 32 + m) * D_DIM + kh * 8;
        #pragma unroll
        for (int i = 0; i < 4; i++) {
            int r = p * 4 + i;
            GLDS(srcb + r * 16, dstb + r * 512);
        }
    };

    stage(0);   // first codebook tile in flight during the x prologue

    // ---- coalesced x prologue through T[1] (two 64-row passes) ----
    // write: [row][dim] fp16, 512 B/row, byte ^= (row&7)<<4 swizzle.
    // read:  lane(m,kh) frag s = halfs [lr][s*16+kh*8..+8) -> ds_read_b128.
    f16x8 bh[16];
    {
        char* xb = (char*)&T[1][0][0];    // 32 KB staging region
        #pragma unroll
        for (int k = 0; k < 2; k++) {
            #pragma unroll
            for (int i = 0; i < 8; i++) {
                int row = i * 8 + w;       // 0..63, whole row per wave-instr
                float4 v = *(const float4*)(
                    x + (size_t)(blkrow + k * 64 + row) * D_DIM + lane * 4);
                f16x4 hv = {(_Float16)v.x, (_Float16)v.y,
                            (_Float16)v.z, (_Float16)v.w};
                u32 byte = (u32)(row * 512 + lane * 8) ^ ((u32)(row & 7) << 4);
                *(f16x4*)(xb + byte) = hv;
            }
            __syncthreads();
            if ((p >> 1) == k) {
                int lr = (p & 1) * 32 + m;
                #pragma unroll
                for (int s = 0; s < 16; s++) {
                    u32 byte = (u32)(lr * 512 + s * 32 + kh * 16)
                             ^ ((u32)(lr & 7) << 4);
                    bh[s] = *(const f16x8*)(xb + byte);
                }
            }
            __syncthreads();
        }
    }
    f16x8 xe = {};
    if (kh == 0) { xe[0] = (_Float16)1.0f; xe[1] = (_Float16)1.0f; }

    u32 A1 = 0, A2 = 0, A3 = 0;

    auto t3 = [](u32& c1, u32& c2, u32& c3, u32 pv) {
        u32 u2 = c1 < pv ? c1 : pv;       // min(c1,pv)
        u32 u3 = c2 < pv ? c2 : pv;       // min(c2,pv)
        c1 = c1 > pv ? c1 : pv;
        c2 = u2 > c2 ? u2 : c2;
        c3 = u3 > c3 ? u3 : c3;
    };

    // main loop: 16 chunks, ONE barrier per chunk.
    // barrier at top: publishes tile c AND retires the buffer stage(c+1)
    // overwrites (it was last read in chunk c-1 / the x prologue).
    for (int c = 0; c < 16; ++c) {
        __syncthreads();
        if (c + 1 < 16) stage(c + 1);
        const f16x8* Af = (const f16x8*)&T[c & 1][h][0];
        f16x8 e = ((const f16x8*)cn2)[h * 512 + c * 32 + m];
        f32x16 a = {};
        #pragma unroll
        for (int s = 0; s < 16; s++) {
            f16x8 fa = Af[(2 * s + kh) * 32 + m];
            a = __builtin_amdgcn_mfma_f32_32x32x16_f16(fa, bh[s], a, 0, 0, 0);
        }
        a = __builtin_amdgcn_mfma_f32_32x32x16_f16(e, xe, a, 0, 0, 0);
        const u32 sbase = (u32)(h * 512 + c * 32) + kh4;
        #pragma unroll
        for (int r = 0; r < 16; r++) {
            u32 code = sbase + (r & 3) + 8 * (r >> 2);
            u32 pk = (f32_sortable(a[r]) & 0xFFFFFC00u) | code;
            t3(A1, A2, A3, pk);
        }
    }

    // merge the two kh-halves of each row (partner lane = lane ^ 32)
    {
        u32 q1 = (u32)__shfl_xor((int)A1, 32, 64);
        u32 q2 = (u32)__shfl_xor((int)A2, 32, 64);
        u32 q3 = (u32)__shfl_xor((int)A3, 32, 64);
        t3(A1, A2, A3, q1); t3(A1, A2, A3, q2); t3(A1, A2, A3, q3);
    }

    // cross-wave (code-half) exchange of per-row top3
    if (kh == 0) {
        int ra = p * 32 + m;
        xchg[h][ra][0] = A1; xchg[h][ra][1] = A2; xchg[h][ra][2] = A3;
    }
    __syncthreads();

    // epilogue: each wave owns 16 rows (local rows w*16 .. w*16+16)
    const int lr = w * 16 + (lane & 15);
    u32 c1 = 0, c2 = 0, c3 = 0;
    #pragma unroll
    for (int hh = 0; hh < 2; hh++) {
        t3(c1, c2, c3, xchg[hh][lr][0]);
        t3(c1, c2, c3, xchg[hh][lr][1]);
        t3(c1, c2, c3, xchg[hh][lr][2]);
    }

    // rescue selection: exact fp32 re-eval when approx margin <= 0.25
    float s1f = f32_unsort(c1), s2f = f32_unsort(c2), s3f = f32_unsort(c3);
    u32 i1 = c1 & 1023u, i2 = c2 & 1023u, i3 = c3 & 1023u;
    const bool act = lane < 16;
    bool need = (s1f - s2f) <= 0.25f;
    if (act && !need) winners[lr] = (int)i1;
    u64 mask = __ballot(act && need);
    while (mask) {
        int r = __ffsll((unsigned long long)mask) - 1;
        mask &= mask - 1;
        int row = blkrow + w * 16 + r;
        u32 d1 = (u32)__shfl((int)i1, r, 64);
        u32 d2 = (u32)__shfl((int)i2, r, 64);
        u32 d3 = (u32)__shfl((int)i3, r, 64);
        float g3 = __shfl(s1f - s3f, r, 64);
        int ncand = (g3 <= 0.25f) ? 3 : 2;
        float4 xv = ((const float4*)(x + (size_t)row * D_DIM))[lane];
        float bs = -3.0e38f; int bi = 0x7fffffff;
        u32 cand[3] = {d1, d2, d3};
        for (int q = 0; q < ncand; q++) {
            int ccd = (int)cand[q];
            float4 ev = ((const float4*)(emb + (size_t)ccd * D_DIM))[lane];
            float d = xv.x * ev.x + xv.y * ev.y + xv.z * ev.z + xv.w * ev.w;
            #pragma unroll
            for (int dd = 1; dd < 64; dd <<= 1) d += __shfl_xor(d, dd, 64);
            float sc = d - cnormf[ccd];
            if (sc > bs || (sc == bs && ccd < bi)) { bs = sc; bi = ccd; }
        }
        if (lane == 0) winners[w * 16 + r] = bi;
    }

    // index write + gather (winners slots are wave-private; no barrier needed)
    if (act) outi[blkrow + lr] = (float)winners[lr];
    #pragma unroll 8
    for (int r = 0; r < 16; r++) {
        int idx = winners[w * 16 + r];
        int row = blkrow + w * 16 + r;
        float4 qv = ((const float4*)(emb + (size_t)idx * D_DIM))[lane];
        ((float4*)(outq + (size_t)row * D_DIM))[lane] = qv;
    }
}

extern "C" void kernel_launch(void* const* d_in, const int* in_sizes, int n_in,
                              void* d_out, int out_size, void* d_ws, size_t ws_size,
                              hipStream_t stream) {
    const float* x   = (const float*)d_in[0];
    const float* emb = (const float*)d_in[1];
    float* outq = (float*)d_out;
    float* outi = outq + (size_t)N_ROWS * D_DIM;

    _Float16* ehi = (_Float16*)d_ws;                              // 512 KB
    _Float16* cn2 = ehi + (size_t)K_EMB * D_DIM;                  // 16 KB
    float* cnormf = (float*)(cn2 + (size_t)K_EMB * 8);            // 4 KB

    vq_prep<<<K_EMB / 4, 256, 0, stream>>>(emb, ehi, cn2, cnormf);
    vq_main<<<N_ROWS / 128, 512, 0, stream>>>(x, emb, ehi, cn2, cnormf,
                                              outq, outi);
}